// Round 1
// baseline (3737.603 us; speedup 1.0000x reference)
//
#include <hip/hip_runtime.h>
#include <stdint.h>

#define B_ 64
#define T_ 2048
#define I_ 256
#define H_ 256
#define G3 768
#define NPROD 192          // producer blocks; 64 + 192 = 256 = CU count (1 block/CU)
#define CH 16              // timesteps per ready-chunk
#define NTILE_N 6          // n-tiles of 128 covering G3=768

typedef _Float16 half2v __attribute__((ext_vector_type(2)));
typedef _Float16 half8v __attribute__((ext_vector_type(8)));

#if __has_builtin(__builtin_amdgcn_fdot2)
#define FDOT2(a, b, c) __builtin_amdgcn_fdot2((a), (b), (c), false)
#else
#define FDOT2(a, b, c) fmaf((float)(a)[1], (float)(b)[1], fmaf((float)(a)[0], (float)(b)[0], (c)))
#endif

__global__ void zero_flags(int* __restrict__ done, int n)
{
  int i = threadIdx.x + blockIdx.x * blockDim.x;
  if (i < n) __hip_atomic_store(&done[i], 0, __ATOMIC_RELAXED, __HIP_MEMORY_SCOPE_AGENT);
}

// One kernel, two roles:
//   blockIdx.x <  64 : consumer (recurrence, one block per batch) -- unchanged math,
//                      but with depth-2 gi prefetch (unroll-by-2, even/odd reg sets).
//   blockIdx.x >= 64 : producer (gi = x@Wih^T + biases), 64x128 tiles, t-major order.
// Producer signals per-CH-timestep chunks via done[] (atomicAdd release, 96 tiles/chunk);
// consumer gates on done[] with an acquire fence. Producers never wait -> no deadlock;
// 256 blocks == 256 CUs so everything is co-resident regardless of dispatch order.
__global__ __launch_bounds__(512) __attribute__((amdgpu_waves_per_eu(2, 2)))
void fused(const float* __restrict__ x, const float* __restrict__ att,
           const int* __restrict__ lengths, const float* __restrict__ Wih,
           const float* __restrict__ Whh, const float* __restrict__ bih,
           const float* __restrict__ bhh, float* __restrict__ gi,
           int* __restrict__ done, float* __restrict__ hws,
           float* __restrict__ out, int t0, int t1)
{
  __shared__ __align__(16) float smem[32 * 68 + 32 * 132];   // producer tiles / consumer hbuf
  const int tid = threadIdx.x;
  const int Tc = t1 - t0;

  if (blockIdx.x >= B_) {
    // ---------------- producer: gi GEMM, 64 batches x 128 outputs per tile ----------------
    const int pid = blockIdx.x - B_;
    float* As = smem;               // [32][68]
    float* Bs = smem + 32 * 68;     // [32][132]
    const int ty = tid >> 5, tx = tid & 31;
    const int lr = tid >> 3;
    const int lk = (tid & 7) << 2;
    const int NT = Tc * NTILE_N;
    for (int i = pid; i < NT; i += NPROD) {
      const int rel = i / NTILE_N;          // t - t0 (t-major => early chunks finish first)
      const int tt  = t0 + rel;
      const int n0  = (i % NTILE_N) << 7;
      float acc[4][4] = {};
      for (int kc = 0; kc < I_; kc += 32) {
        float4 a0 = *(const float4*)(x + ((size_t)lr * T_ + tt) * I_ + kc + lk);
        float4 b0 = *(const float4*)(Wih + (size_t)(n0 + lr) * I_ + kc + lk);
        float4 b1 = *(const float4*)(Wih + (size_t)(n0 + lr + 64) * I_ + kc + lk);
        __syncthreads();
        As[(lk + 0) * 68 + lr] = a0.x; As[(lk + 1) * 68 + lr] = a0.y;
        As[(lk + 2) * 68 + lr] = a0.z; As[(lk + 3) * 68 + lr] = a0.w;
        Bs[(lk + 0) * 132 + lr] = b0.x; Bs[(lk + 1) * 132 + lr] = b0.y;
        Bs[(lk + 2) * 132 + lr] = b0.z; Bs[(lk + 3) * 132 + lr] = b0.w;
        Bs[(lk + 0) * 132 + lr + 64] = b1.x; Bs[(lk + 1) * 132 + lr + 64] = b1.y;
        Bs[(lk + 2) * 132 + lr + 64] = b1.z; Bs[(lk + 3) * 132 + lr + 64] = b1.w;
        __syncthreads();
        #pragma unroll
        for (int kk = 0; kk < 32; ++kk) {
          float4 av = *(const float4*)(&As[kk * 68 + (ty << 2)]);
          float4 bv = *(const float4*)(&Bs[kk * 132 + (tx << 2)]);
          float av_[4] = {av.x, av.y, av.z, av.w};
          float bv_[4] = {bv.x, bv.y, bv.z, bv.w};
          #pragma unroll
          for (int u = 0; u < 4; ++u)
            #pragma unroll
            for (int v = 0; v < 4; ++v)
              acc[u][v] = fmaf(av_[u], bv_[v], acc[u][v]);
        }
      }
      const int colb = n0 + (tx << 2);
      float4 bi = *(const float4*)(bih + colb);
      float4 bh = *(const float4*)(bhh + colb);
      float4 badd;
      badd.x = bi.x + (colb + 0 < 512 ? bh.x : 0.f);
      badd.y = bi.y + (colb + 1 < 512 ? bh.y : 0.f);
      badd.z = bi.z + (colb + 2 < 512 ? bh.z : 0.f);
      badd.w = bi.w + (colb + 3 < 512 ? bh.w : 0.f);
      float* gout = gi + (size_t)rel * B_ * G3;
      #pragma unroll
      for (int r = 0; r < 4; ++r) {
        const int bb = (ty << 2) + r;
        float4 o;
        o.x = acc[r][0] + badd.x; o.y = acc[r][1] + badd.y;
        o.z = acc[r][2] + badd.z; o.w = acc[r][3] + badd.w;
        *(float4*)(gout + (size_t)bb * G3 + colb) = o;
      }
      // all 512 threads' stores drained by the vmcnt(0) in __syncthreads, then one
      // agent-scope fence (L2 writeback) + release add makes the tile visible.
      __syncthreads();
      if (tid == 0) {
        __threadfence();
        __hip_atomic_fetch_add(&done[rel >> 4], 1, __ATOMIC_RELEASE, __HIP_MEMORY_SCOPE_AGENT);
      }
    }
    return;
  }

  // ---------------- consumer: per-batch recurrence ----------------
  const int b  = blockIdx.x;
  const int j  = tid >> 1;
  const int s  = tid & 1;
  const int k0 = s << 7;
  _Float16* hbuf = (_Float16*)smem;   // [2][272], slice stride 136 halves

  // W_hh rows -> packed fp16 in registers (prologue only)
  half2v w[192];
  #pragma unroll
  for (int g = 0; g < 3; ++g) {
    const float* row = Whh + (size_t)(g * 256 + j) * H_ + k0;
    #pragma unroll
    for (int q = 0; q < 32; ++q) {
      float4 v = *(const float4*)(row + (q << 2));
      half2v a, c;
      a[0] = (_Float16)v.x; a[1] = (_Float16)v.y;
      c[0] = (_Float16)v.z; c[1] = (_Float16)v.w;
      w[g * 64 + 2 * q]     = a;
      w[g * 64 + 2 * q + 1] = c;
    }
  }

  float bhn = 0.f, h_reg = 0.f;
  if (s == 0) {
    bhn = bhh[512 + j];
    h_reg = (t0 > 0) ? hws[b * H_ + j] : 0.f;
  }
  if (tid < 256) {
    float v = (t0 > 0) ? hws[b * H_ + tid] : 0.f;
    hbuf[(tid >> 7) * 136 + (tid & 127)] = (_Float16)v;
  }
  int len = lengths[b]; if (len > t1) len = t1;
  const int nch = (Tc + CH - 1) / CH;
  int wm = -1;   // highest chunk known ready
  __syncthreads();

  // Gate: ensure chunks <= NEED are produced. Uniform branch; barrier only on crossing.
#define GATE(NEED) do {                                                               \
    int need_ = (NEED); if (need_ > nch - 1) need_ = nch - 1;                         \
    if (need_ > wm) {                                                                 \
      if (tid == 0) {                                                                 \
        for (int c_ = wm + 1; c_ <= need_; ++c_) {                                    \
          int exp_ = ((Tc - c_ * CH) < CH ? (Tc - c_ * CH) : CH) * NTILE_N;           \
          while (__hip_atomic_load(&done[c_], __ATOMIC_RELAXED,                       \
                                   __HIP_MEMORY_SCOPE_AGENT) < exp_)                  \
            __builtin_amdgcn_s_sleep(2);                                              \
        }                                                                             \
      }                                                                               \
      __syncthreads();                                                                \
      __threadfence();  /* acquire side: invalidate stale L1/L2 gi lines */           \
      wm = need_;                                                                     \
    }                                                                                 \
  } while (0)

  // One recurrence step. Consumes (GR,GZ,GN,WAT); mid-step reloads them for TT+2
  // (depth-2 prefetch: ~2 full steps between issue and the vmcnt wait).
#define STEP(GR, GZ, GN, WAT, TT, RELOAD_OK) do {                                     \
    float accr = 0.f, accz = 0.f, accn = 0.f;                                         \
    const _Float16* hb = hbuf + p * 272 + s * 136;                                    \
    _Pragma("unroll")                                                                 \
    for (int q = 0; q < 16; ++q) {                                                    \
      half8v hv = *(const half8v*)(hb + (q << 3));                                    \
      half2v h0_ = __builtin_shufflevector(hv, hv, 0, 1);                             \
      half2v h1_ = __builtin_shufflevector(hv, hv, 2, 3);                             \
      half2v h2_ = __builtin_shufflevector(hv, hv, 4, 5);                             \
      half2v h3_ = __builtin_shufflevector(hv, hv, 6, 7);                             \
      const int qq = q << 2;                                                          \
      accr = FDOT2(w[qq + 0], h0_, accr);                                             \
      accr = FDOT2(w[qq + 1], h1_, accr);                                             \
      accr = FDOT2(w[qq + 2], h2_, accr);                                             \
      accr = FDOT2(w[qq + 3], h3_, accr);                                             \
      accz = FDOT2(w[64 + qq + 0], h0_, accz);                                        \
      accz = FDOT2(w[64 + qq + 1], h1_, accz);                                        \
      accz = FDOT2(w[64 + qq + 2], h2_, accz);                                        \
      accz = FDOT2(w[64 + qq + 3], h3_, accz);                                        \
      accn = FDOT2(w[128 + qq + 0], h0_, accn);                                       \
      accn = FDOT2(w[128 + qq + 1], h1_, accn);                                       \
      accn = FDOT2(w[128 + qq + 2], h2_, accn);                                       \
      accn = FDOT2(w[128 + qq + 3], h3_, accn);                                       \
    }                                                                                 \
    accr += __shfl_xor(accr, 1);                                                      \
    accz += __shfl_xor(accz, 1);                                                      \
    accn += __shfl_xor(accn, 1);                                                      \
    if (s == 0) {                                                                     \
      float r_ = 1.f / (1.f + __expf(-(accr + GR)));                                  \
      float z_ = 1.f / (1.f + __expf(-(accz + GZ)));                                  \
      float e2_ = __expf(2.f * (GN + r_ * (accn + bhn)));                             \
      float nn_ = 1.f - 2.f / (e2_ + 1.f);                                            \
      float hnew_ = (1.f - z_) * nn_ + z_ * h_reg;                                    \
      h_reg = (WAT) * hnew_ + (1.f - (WAT)) * h_reg;                                  \
      hbuf[(p ^ 1) * 272 + (j >> 7) * 136 + (j & 127)] = (_Float16)h_reg;             \
      if (RELOAD_OK) {                                                                \
        const float* gb_ = gi + ((size_t)((TT) + 2 - t0) * B_ + b) * G3;              \
        GR = gb_[j]; GZ = gb_[256 + j]; GN = gb_[512 + j];                            \
        WAT = att[(size_t)b * T_ + (TT) + 2];                                         \
      }                                                                               \
    }                                                                                 \
    __syncthreads();                                                                  \
    p ^= 1;                                                                           \
  } while (0)

  GATE(0);
  // depth-2 prefetch register sets: e_* for even-parity steps, o_* for odd.
  float e_gr = 0.f, e_gz = 0.f, e_gn = 0.f, e_wat = 0.f;
  float o_gr = 0.f, o_gz = 0.f, o_gn = 0.f, o_wat = 0.f;
  if (s == 0 && t0 < len) {
    const float* gb = gi + (size_t)b * G3;
    e_gr = gb[j]; e_gz = gb[256 + j]; e_gn = gb[512 + j];
    e_wat = att[(size_t)b * T_ + t0];
  }
  if (s == 0 && t0 + 1 < len) {
    const float* gb = gi + ((size_t)B_ + b) * G3;
    o_gr = gb[j]; o_gz = gb[256 + j]; o_gn = gb[512 + j];
    o_wat = att[(size_t)b * T_ + t0 + 1];
  }

  int p = 0;
  int t = t0;
  for (; t + 1 < len; t += 2) {
    GATE((t + 3 - t0) >> 4);
    STEP(e_gr, e_gz, e_gn, e_wat, t,     (t + 2 < len));
    STEP(o_gr, o_gz, o_gn, o_wat, t + 1, (t + 3 < len));
  }
  if (t < len) {
    STEP(e_gr, e_gz, e_gn, e_wat, t, false);   // tail (odd remaining count)
  }

  if (s == 0) {
    hws[b * H_ + j] = h_reg;
    if (t1 == T_) out[b * H_ + j] = h_reg;
  }
#undef STEP
#undef GATE
}

extern "C" void kernel_launch(void* const* d_in, const int* in_sizes, int n_in,
                              void* d_out, int out_size, void* d_ws, size_t ws_size,
                              hipStream_t stream)
{
  const float* x       = (const float*)d_in[0];
  const float* att     = (const float*)d_in[1];
  const int*   lengths = (const int*)d_in[2];
  const float* Wih     = (const float*)d_in[3];
  const float* Whh     = (const float*)d_in[4];
  const float* bih     = (const float*)d_in[5];
  const float* bhh     = (const float*)d_in[6];
  float* out = (float*)d_out;

  // workspace layout: [0,4K) chunk flags | [4K, 4K+64K) h carry | gi tiles after
  int*   done = (int*)d_ws;
  float* hws  = (float*)((char*)d_ws + 4096);
  float* gi   = (float*)((char*)d_ws + 4096 + 65536);
  const size_t used0 = 4096 + 65536;
  const size_t per_t = (size_t)B_ * G3 * sizeof(float);
  size_t avail = ws_size > used0 ? ws_size - used0 : 0;
  int Tc = (int)(avail / per_t);
  if (Tc > T_) Tc = T_;
  if (Tc < 1) Tc = 1;

  for (int t0 = 0; t0 < T_; t0 += Tc) {
    int t1 = t0 + Tc; if (t1 > T_) t1 = T_;
    int nch = (t1 - t0 + CH - 1) / CH;
    zero_flags<<<dim3((nch + 127) / 128), 128, 0, stream>>>(done, nch);
    fused<<<dim3(B_ + NPROD), 512, 0, stream>>>(x, att, lengths, Wih, Whh, bih, bhh,
                                                gi, done, hws, out, t0, t1);
  }
}

// Round 2
// 3553.714 us; speedup vs baseline: 1.0517x; 1.0517x over previous
//
#include <hip/hip_runtime.h>
#include <stdint.h>

#define B_ 64
#define T_ 2048
#define I_ 256
#define H_ 256
#define G3 768
#define NPROD 192          // producer blocks; 64 + 192 = 256 = CU count (1 block/CU)
#define CH 16              // timesteps per ready-chunk
#define NTILE_N 6          // n-tiles of 128 covering G3=768

typedef _Float16 half2v __attribute__((ext_vector_type(2)));
typedef _Float16 half8v __attribute__((ext_vector_type(8)));

#if __has_builtin(__builtin_amdgcn_fdot2)
#define FDOT2(a, b, c) __builtin_amdgcn_fdot2((a), (b), (c), false)
#else
#define FDOT2(a, b, c) fmaf((float)(a)[1], (float)(b)[1], fmaf((float)(a)[0], (float)(b)[0], (c)))
#endif

__global__ void zero_flags(int* __restrict__ done, int n)
{
  int i = threadIdx.x + blockIdx.x * blockDim.x;
  if (i < n) __hip_atomic_store(&done[i], 0, __ATOMIC_RELAXED, __HIP_MEMORY_SCOPE_AGENT);
}

// One kernel, two roles (1 block/CU, 256 blocks = 256 CUs, all co-resident):
//   blockIdx.x <  64 : consumer (per-batch recurrence)
//   blockIdx.x >= 64 : producer (gi = x@Wih^T + biases), t-major 64x128 tiles
// Producer signals per-CH-timestep chunks via done[] (release add after syncthreads+fence);
// consumer gates with acquire. Producers never wait -> no deadlock.
//
// CRITICAL (round-1 lesson): __syncthreads() == s_waitcnt vmcnt(0); s_barrier.
// gi prefetch loads MUST be issued at the TOP of a step so the end-of-step barrier's
// vmcnt(0) drain comes ~a full step (~1300 cy) after issue, covering HBM latency.
__global__ __launch_bounds__(512) __attribute__((amdgpu_waves_per_eu(2, 2)))
void fused(const float* __restrict__ x, const float* __restrict__ att,
           const int* __restrict__ lengths, const float* __restrict__ Wih,
           const float* __restrict__ Whh, const float* __restrict__ bih,
           const float* __restrict__ bhh, float* __restrict__ gi,
           int* __restrict__ done, float* __restrict__ hws,
           float* __restrict__ out, int t0, int t1)
{
  __shared__ __align__(16) float smem[32 * 68 + 32 * 132];   // 25600 B, both roles
  const int tid = threadIdx.x;
  const int Tc = t1 - t0;

  if (blockIdx.x >= B_) {
    // ---------------- producer: gi GEMM ----------------
    const int pid = blockIdx.x - B_;
    float* As = smem;               // [32][68]
    float* Bs = smem + 32 * 68;     // [32][132]
    const int ty = tid >> 5, tx = tid & 31;
    const int lr = tid >> 3;
    const int lk = (tid & 7) << 2;
    const int NT = Tc * NTILE_N;
    for (int i = pid; i < NT; i += NPROD) {
      const int rel = i / NTILE_N;          // t - t0 (t-major => early chunks finish first)
      const int tt  = t0 + rel;
      const int n0  = (i % NTILE_N) << 7;
      float acc[4][4] = {};
      for (int kc = 0; kc < I_; kc += 32) {
        float4 a0 = *(const float4*)(x + ((size_t)lr * T_ + tt) * I_ + kc + lk);
        float4 b0 = *(const float4*)(Wih + (size_t)(n0 + lr) * I_ + kc + lk);
        float4 b1 = *(const float4*)(Wih + (size_t)(n0 + lr + 64) * I_ + kc + lk);
        __syncthreads();
        As[(lk + 0) * 68 + lr] = a0.x; As[(lk + 1) * 68 + lr] = a0.y;
        As[(lk + 2) * 68 + lr] = a0.z; As[(lk + 3) * 68 + lr] = a0.w;
        Bs[(lk + 0) * 132 + lr] = b0.x; Bs[(lk + 1) * 132 + lr] = b0.y;
        Bs[(lk + 2) * 132 + lr] = b0.z; Bs[(lk + 3) * 132 + lr] = b0.w;
        Bs[(lk + 0) * 132 + lr + 64] = b1.x; Bs[(lk + 1) * 132 + lr + 64] = b1.y;
        Bs[(lk + 2) * 132 + lr + 64] = b1.z; Bs[(lk + 3) * 132 + lr + 64] = b1.w;
        __syncthreads();
        #pragma unroll
        for (int kk = 0; kk < 32; ++kk) {
          float4 av = *(const float4*)(&As[kk * 68 + (ty << 2)]);
          float4 bv = *(const float4*)(&Bs[kk * 132 + (tx << 2)]);
          float av_[4] = {av.x, av.y, av.z, av.w};
          float bv_[4] = {bv.x, bv.y, bv.z, bv.w};
          #pragma unroll
          for (int u = 0; u < 4; ++u)
            #pragma unroll
            for (int v = 0; v < 4; ++v)
              acc[u][v] = fmaf(av_[u], bv_[v], acc[u][v]);
        }
      }
      const int colb = n0 + (tx << 2);
      float4 bi = *(const float4*)(bih + colb);
      float4 bh = *(const float4*)(bhh + colb);
      float4 badd;
      badd.x = bi.x + (colb + 0 < 512 ? bh.x : 0.f);
      badd.y = bi.y + (colb + 1 < 512 ? bh.y : 0.f);
      badd.z = bi.z + (colb + 2 < 512 ? bh.z : 0.f);
      badd.w = bi.w + (colb + 3 < 512 ? bh.w : 0.f);
      float* gout = gi + (size_t)rel * B_ * G3;
      #pragma unroll
      for (int r = 0; r < 4; ++r) {
        const int bb = (ty << 2) + r;
        float4 o;
        o.x = acc[r][0] + badd.x; o.y = acc[r][1] + badd.y;
        o.z = acc[r][2] + badd.z; o.w = acc[r][3] + badd.w;
        *(float4*)(gout + (size_t)bb * G3 + colb) = o;
      }
      __syncthreads();   // vmcnt(0): all 512 threads' stores drained
      if (tid == 0) {
        __threadfence();
        __hip_atomic_fetch_add(&done[rel >> 4], 1, __ATOMIC_RELEASE, __HIP_MEMORY_SCOPE_AGENT);
      }
    }
    return;
  }

  // ---------------- consumer: per-batch recurrence ----------------
  const int b  = blockIdx.x;
  const int j  = tid >> 1;
  const int s  = tid & 1;
  const int k0 = s << 7;
  _Float16* hbuf  = (_Float16*)smem;        // [2][272] halves (1088 B)
  float*    att_s = smem + 384;             // Tc floats (<= 8 KiB), starts at byte 1536

  // W_hh rows -> packed fp16 in registers (prologue only)
  half2v w[192];
  #pragma unroll
  for (int g = 0; g < 3; ++g) {
    const float* row = Whh + (size_t)(g * 256 + j) * H_ + k0;
    #pragma unroll
    for (int q = 0; q < 32; ++q) {
      float4 v = *(const float4*)(row + (q << 2));
      half2v a, c;
      a[0] = (_Float16)v.x; a[1] = (_Float16)v.y;
      c[0] = (_Float16)v.z; c[1] = (_Float16)v.w;
      w[g * 64 + 2 * q]     = a;
      w[g * 64 + 2 * q + 1] = c;
    }
  }

  float bhn = 0.f, h_reg = 0.f;
  if (s == 0) {
    bhn = bhh[512 + j];
    h_reg = (t0 > 0) ? hws[b * H_ + j] : 0.f;
  }
  if (tid < 256) {
    float v = (t0 > 0) ? hws[b * H_ + tid] : 0.f;
    hbuf[(tid >> 7) * 136 + (tid & 127)] = (_Float16)v;
  }
  // stage this block's att slice into LDS (input data, no gating needed)
  for (int i = tid; i < Tc; i += 512) att_s[i] = att[(size_t)b * T_ + t0 + i];
  int len = lengths[b]; if (len > t1) len = t1;
  const int nch = (Tc + CH - 1) / CH;
  int wm = -1;   // highest chunk known ready
  __syncthreads();

#define GATE(NEED) do {                                                               \
    int need_ = (NEED); if (need_ > nch - 1) need_ = nch - 1;                         \
    if (need_ > wm) {                                                                 \
      if (tid == 0) {                                                                 \
        for (int c_ = wm + 1; c_ <= need_; ++c_) {                                    \
          int exp_ = ((Tc - c_ * CH) < CH ? (Tc - c_ * CH) : CH) * NTILE_N;           \
          while (__hip_atomic_load(&done[c_], __ATOMIC_RELAXED,                       \
                                   __HIP_MEMORY_SCOPE_AGENT) < exp_)                  \
            __builtin_amdgcn_s_sleep(2);                                              \
        }                                                                             \
      }                                                                               \
      __syncthreads();                                                                \
      __threadfence();  /* acquire: order flag-read before subsequent gi loads */     \
      wm = need_;                                                                     \
    }                                                                                 \
  } while (0)

  // One step. Issues gi loads for TT+2 into the N-set at the TOP (full-step cover
  // before the end-of-step barrier's vmcnt(0) drain); consumes the C-set at the end.
#define STEP(CGR, CGZ, CGN, NGR, NGZ, NGN, TT, ISSUE_OK) do {                         \
    if (s == 0 && (ISSUE_OK)) {                                                       \
      const float* gb_ = gi + ((size_t)((TT) + 2 - t0) * B_ + b) * G3;                \
      NGR = gb_[j]; NGZ = gb_[256 + j]; NGN = gb_[512 + j];                           \
    }                                                                                 \
    float wat_ = (s == 0) ? att_s[(TT) - t0] : 0.f;                                   \
    float accr = 0.f, accz = 0.f, accn = 0.f;                                         \
    const _Float16* hb = hbuf + p * 272 + s * 136;                                    \
    _Pragma("unroll")                                                                 \
    for (int q = 0; q < 16; ++q) {                                                    \
      half8v hv = *(const half8v*)(hb + (q << 3));                                    \
      half2v h0_ = __builtin_shufflevector(hv, hv, 0, 1);                             \
      half2v h1_ = __builtin_shufflevector(hv, hv, 2, 3);                             \
      half2v h2_ = __builtin_shufflevector(hv, hv, 4, 5);                             \
      half2v h3_ = __builtin_shufflevector(hv, hv, 6, 7);                             \
      const int qq = q << 2;                                                          \
      accr = FDOT2(w[qq + 0], h0_, accr);                                             \
      accr = FDOT2(w[qq + 1], h1_, accr);                                             \
      accr = FDOT2(w[qq + 2], h2_, accr);                                             \
      accr = FDOT2(w[qq + 3], h3_, accr);                                             \
      accz = FDOT2(w[64 + qq + 0], h0_, accz);                                        \
      accz = FDOT2(w[64 + qq + 1], h1_, accz);                                        \
      accz = FDOT2(w[64 + qq + 2], h2_, accz);                                        \
      accz = FDOT2(w[64 + qq + 3], h3_, accz);                                        \
      accn = FDOT2(w[128 + qq + 0], h0_, accn);                                       \
      accn = FDOT2(w[128 + qq + 1], h1_, accn);                                       \
      accn = FDOT2(w[128 + qq + 2], h2_, accn);                                       \
      accn = FDOT2(w[128 + qq + 3], h3_, accn);                                       \
    }                                                                                 \
    accr += __shfl_xor(accr, 1);                                                      \
    accz += __shfl_xor(accz, 1);                                                      \
    accn += __shfl_xor(accn, 1);                                                      \
    if (s == 0) {                                                                     \
      float r_ = 1.f / (1.f + __expf(-(accr + CGR)));                                 \
      float z_ = 1.f / (1.f + __expf(-(accz + CGZ)));                                 \
      float e2_ = __expf(2.f * (CGN + r_ * (accn + bhn)));                            \
      float nn_ = 1.f - 2.f / (e2_ + 1.f);                                            \
      float hnew_ = (1.f - z_) * nn_ + z_ * h_reg;                                    \
      h_reg = wat_ * hnew_ + (1.f - wat_) * h_reg;                                    \
      hbuf[(p ^ 1) * 272 + (j >> 7) * 136 + (j & 127)] = (_Float16)h_reg;             \
    }                                                                                 \
    __syncthreads();                                                                  \
    p ^= 1;                                                                           \
  } while (0)

  GATE(0);
  float e_gr = 0.f, e_gz = 0.f, e_gn = 0.f;
  float o_gr = 0.f, o_gz = 0.f, o_gn = 0.f;
  float e2_gr = 0.f, e2_gz = 0.f, e2_gn = 0.f;
  float o2_gr = 0.f, o2_gz = 0.f, o2_gn = 0.f;
  if (s == 0 && t0 < len) {
    const float* gb = gi + (size_t)b * G3;
    e_gr = gb[j]; e_gz = gb[256 + j]; e_gn = gb[512 + j];
  }
  if (s == 0 && t0 + 1 < len) {
    const float* gb = gi + ((size_t)B_ + b) * G3;
    o_gr = gb[j]; o_gz = gb[256 + j]; o_gn = gb[512 + j];
  }

  int p = 0;
  int t = t0;
  for (; t + 1 < len; t += 2) {
    GATE((t + 3 - t0) >> 4);
    STEP(e_gr, e_gz, e_gn, e2_gr, e2_gz, e2_gn, t,     (t + 2 < len));
    STEP(o_gr, o_gz, o_gn, o2_gr, o2_gz, o2_gn, t + 1, (t + 3 < len));
    e_gr = e2_gr; e_gz = e2_gz; e_gn = e2_gn;
    o_gr = o2_gr; o_gz = o2_gz; o_gn = o2_gn;
  }
  if (t < len) {
    STEP(e_gr, e_gz, e_gn, e2_gr, e2_gz, e2_gn, t, false);   // tail
  }

  if (s == 0) {
    hws[b * H_ + j] = h_reg;
    if (t1 == T_) out[b * H_ + j] = h_reg;
  }
#undef STEP
#undef GATE
}

extern "C" void kernel_launch(void* const* d_in, const int* in_sizes, int n_in,
                              void* d_out, int out_size, void* d_ws, size_t ws_size,
                              hipStream_t stream)
{
  const float* x       = (const float*)d_in[0];
  const float* att     = (const float*)d_in[1];
  const int*   lengths = (const int*)d_in[2];
  const float* Wih     = (const float*)d_in[3];
  const float* Whh     = (const float*)d_in[4];
  const float* bih     = (const float*)d_in[5];
  const float* bhh     = (const float*)d_in[6];
  float* out = (float*)d_out;

  // workspace layout: [0,4K) chunk flags | [4K, 4K+64K) h carry | gi after
  int*   done = (int*)d_ws;
  float* hws  = (float*)((char*)d_ws + 4096);
  float* gi   = (float*)((char*)d_ws + 4096 + 65536);
  const size_t used0 = 4096 + 65536;
  const size_t per_t = (size_t)B_ * G3 * sizeof(float);
  size_t avail = ws_size > used0 ? ws_size - used0 : 0;
  int Tc = (int)(avail / per_t);
  if (Tc > T_) Tc = T_;
  if (Tc < 1) Tc = 1;

  for (int t0 = 0; t0 < T_; t0 += Tc) {
    int t1 = t0 + Tc; if (t1 > T_) t1 = T_;
    int nch = (t1 - t0 + CH - 1) / CH;
    zero_flags<<<dim3((nch + 127) / 128), 128, 0, stream>>>(done, nch);
    fused<<<dim3(B_ + NPROD), 512, 0, stream>>>(x, att, lengths, Wih, Whh, bih, bhh,
                                                gi, done, hws, out, t0, t1);
  }
}